// Round 8
// baseline (317.514 us; speedup 1.0000x reference)
//
#include <hip/hip_runtime.h>

#define SCALE 0.0625f  // C^-0.5 = 1/16

typedef __attribute__((ext_vector_type(4))) float f32x4;
typedef __attribute__((ext_vector_type(8))) short s16x8;

__device__ __forceinline__ unsigned short f2bf(float x) {
    unsigned u = __float_as_uint(x);
    u = u + 0x7FFF + ((u >> 16) & 1);   // RNE; inputs finite
    return (unsigned short)(u >> 16);
}

// ---------------------------------------------------------------------------
// prep1: blocks 0..15  -> q[b,c] = TO[b] . Wq[c] + bq[c]
//        blocks 16..31 -> WvB = bf16(Wv)   (row-major [co][o])
// ---------------------------------------------------------------------------
__global__ __launch_bounds__(256) void prep1_kernel(
    const float* __restrict__ TO,    // [2,1024]
    const float* __restrict__ Wq,    // [256,1024]
    const float* __restrict__ bq,    // [256]
    const float* __restrict__ Wv,    // [256,256]
    float* __restrict__ qbuf,        // [2,256]
    unsigned short* __restrict__ WvB)// [256,256] bf16
{
    const int blk = blockIdx.x;
    const int t   = threadIdx.x;
    if (blk < 16) {
        const int b    = blk >> 3;
        const int rblk = blk & 7;
        const int wv = t >> 6, l = t & 63;
        const float4* Wq4 = (const float4*)Wq;
        const float4* TO4 = (const float4*)TO;
        for (int rr = 0; rr < 8; ++rr) {
            const int c = rblk * 32 + wv * 8 + rr;
            float acc = 0.f;
#pragma unroll
            for (int i = 0; i < 4; ++i) {
                float4 wq = Wq4[c * 256 + i * 64 + l];
                float4 tv = TO4[b * 256 + i * 64 + l];
                acc = fmaf(wq.x, tv.x, acc);
                acc = fmaf(wq.y, tv.y, acc);
                acc = fmaf(wq.z, tv.z, acc);
                acc = fmaf(wq.w, tv.w, acc);
            }
#pragma unroll
            for (int mask = 1; mask < 64; mask <<= 1)
                acc += __shfl_xor(acc, mask, 64);
            if (l == 0) qbuf[b * 256 + c] = acc + bq[c];
        }
    } else {
        const int idx = blk - 16;   // 0..15, 4096 elements each
#pragma unroll
        for (int i = 0; i < 4; ++i) {
            const int e = idx * 4096 + i * 1024 + t * 4;
            const float4 f = ((const float4*)Wv)[e >> 2];
            ushort4 o;
            o.x = f2bf(f.x); o.y = f2bf(f.y);
            o.z = f2bf(f.z); o.w = f2bf(f.w);
            *(ushort4*)(WvB + e) = o;
        }
    }
}

// ---------------------------------------------------------------------------
// prep2: 16 blocks: qks[b,cp] = SCALE * sum_c q[c] Wk[c][cp]
// (q.bk term dropped: softmax-invariant)
// ---------------------------------------------------------------------------
__global__ __launch_bounds__(256) void prep2_kernel(
    const float* __restrict__ qbuf,  // [2,256]
    const float* __restrict__ Wk,    // [256,256]
    float* __restrict__ qks)         // [2,256] (pre-scaled)
{
    const int blk = blockIdx.x;
    const int t   = threadIdx.x;
    const int b = blk >> 3, j = blk & 7;
    const int col = t & 31, chunk = t >> 5;
    const int cp = j * 32 + col;
    float partial = 0.f;
#pragma unroll 8
    for (int cc = 0; cc < 32; ++cc) {
        const int c = chunk * 32 + cc;
        partial = fmaf(qbuf[b * 256 + c], Wk[c * 256 + cp], partial);
    }
    __shared__ float r2[8][32];
    r2[chunk][col] = partial;
    __syncthreads();
    if (t < 32) {
        float s = 0.f;
#pragma unroll
        for (int k = 0; k < 8; ++k) s += r2[k][t];
        qks[b * 256 + j * 32 + t] = SCALE * s;
    }
}

// ---------------------------------------------------------------------------
// scores: 2048 blocks = bm(32) x cs(16) x pxq(4); 256 thr, NO LDS.
//   8 blocks/CU -> 32 waves/CU (the point of this round: latency hiding).
//   Thread = one px-float4 x 16 channels (c = 16cs..16cs+15): 16 dwordx4
//   loads feeding 4 independent accumulator chains -> many loads in flight.
//   part[cs][bm][px] = sum_{c in chunk} qks[c] * X[bm,c,px]
// ---------------------------------------------------------------------------
__global__ __launch_bounds__(256) void scores_kernel(
    const float* __restrict__ X,      // [2,16,256,4096]
    const float* __restrict__ qks,    // [2,256]
    float* __restrict__ part)         // [16][32][4096]
{
    const int blk = blockIdx.x;
    const int bm  = blk >> 6;          // 0..31
    const int cs  = (blk >> 2) & 15;   // 0..15
    const int pxq = blk & 3;           // px quarter (1024 px = 256 f4)
    const int b   = bm >> 4;
    const int t   = threadIdx.x;

    const float4* __restrict__ Xr =
        (const float4*)X + bm * 262144 + cs * 16384 + pxq * 256 + t;
    const float* __restrict__ qr = qks + b * 256 + cs * 16;

    float4 a0 = {0,0,0,0}, a1 = {0,0,0,0}, a2 = {0,0,0,0}, a3 = {0,0,0,0};
#pragma unroll
    for (int j = 0; j < 16; j += 4) {
        const float4 x0 = Xr[(j + 0) * 1024];
        const float4 x1 = Xr[(j + 1) * 1024];
        const float4 x2 = Xr[(j + 2) * 1024];
        const float4 x3 = Xr[(j + 3) * 1024];
        const float q0 = qr[j + 0], q1 = qr[j + 1];
        const float q2 = qr[j + 2], q3 = qr[j + 3];
        a0.x = fmaf(q0, x0.x, a0.x); a0.y = fmaf(q0, x0.y, a0.y);
        a0.z = fmaf(q0, x0.z, a0.z); a0.w = fmaf(q0, x0.w, a0.w);
        a1.x = fmaf(q1, x1.x, a1.x); a1.y = fmaf(q1, x1.y, a1.y);
        a1.z = fmaf(q1, x1.z, a1.z); a1.w = fmaf(q1, x1.w, a1.w);
        a2.x = fmaf(q2, x2.x, a2.x); a2.y = fmaf(q2, x2.y, a2.y);
        a2.z = fmaf(q2, x2.z, a2.z); a2.w = fmaf(q2, x2.w, a2.w);
        a3.x = fmaf(q3, x3.x, a3.x); a3.y = fmaf(q3, x3.y, a3.y);
        a3.z = fmaf(q3, x3.z, a3.z); a3.w = fmaf(q3, x3.w, a3.w);
    }
    float4 s;
    s.x = (a0.x + a1.x) + (a2.x + a3.x);
    s.y = (a0.y + a1.y) + (a2.y + a3.y);
    s.z = (a0.z + a1.z) + (a2.z + a3.z);
    s.w = (a0.w + a1.w) + (a2.w + a3.w);
    ((float4*)part)[(cs * 32 + bm) * 1024 + pxq * 256 + t] = s;
}

// ---------------------------------------------------------------------------
// softmax: 32 blocks = b(2) x pxchunk(16); 256 thr, thread = 1 px.
//   s[m] = sum_cs part[cs][b*16+m][px]; probs = exp(s)/sum (max-free).
//   part is L2-class (8 MB).
// ---------------------------------------------------------------------------
__global__ __launch_bounds__(256) void softmax_kernel(
    const float* __restrict__ part,   // [16][32][4096]
    float* __restrict__ probs)        // [2][16][4096]
{
    const int blk = blockIdx.x;
    const int b   = blk >> 4;
    const int px  = ((blk & 15) << 8) + threadIdx.x;
    float e[16];
    float tot = 0.f;
#pragma unroll
    for (int m = 0; m < 16; ++m) {
        float s = 0.f;
#pragma unroll
        for (int cc = 0; cc < 16; ++cc)
            s += part[(cc * 32 + b * 16 + m) * 4096 + px];
        e[m] = __expf(s);
        tot += e[m];
    }
    const float inv = 1.0f / tot;
#pragma unroll
    for (int m = 0; m < 16; ++m)
        probs[(b * 16 + m) * 4096 + px] = e[m] * inv;
}

// ---------------------------------------------------------------------------
// wxconv: 512 blocks x 512 thr (16 waves/CU in the m-loop). Block = 16 px.
//   preamble: probs[16m x 16px] -> LDS pl (1 barrier).
//   m-loop  : SPLIT across two 256-thr groups (g=0: m 0-7, g=1: m 8-15);
//             within group: p4 = t&3 (f4 over 16 px), cg = (t>>2)&63
//             (c = cg+64k). Double-buffered, zero barriers inside.
//             X is L3-resident from the scores pass.
//   combine : g0 writes slab, barrier, g1 adds, barrier.
//   epilogue: verified bf16 MFMA conv, 8 waves x 2 co-tiles.
// ---------------------------------------------------------------------------
__global__ __launch_bounds__(512, 1) void wxconv_kernel(
    const float* __restrict__ X,      // [2,16,256,4096]
    const float* __restrict__ probs,  // [2][16][4096]
    const unsigned short* __restrict__ WvB,  // [256,256] bf16
    const float* __restrict__ bv,     // [256]
    float* __restrict__ out)          // [2,256,4096]
{
    const int t   = threadIdx.x;
    const int blk = blockIdx.x;
    const int pb  = ((blk & 7) << 6) | (blk >> 3);   // XCD swizzle
    const int b   = pb >> 8;
    const int hw0 = (pb & 255) << 4;                 // 16 pixels

    __shared__ float pl[16][16];      // probs [m][px]
    __shared__ float slab[256 * 20];  // wx[c][px], stride 20

    if (t < 256)
        pl[t >> 4][t & 15] = probs[(b * 16 + (t >> 4)) * 4096 + hw0 + (t & 15)];
    __syncthreads();

    const int g    = t >> 8;          // m-half group
    const int tl   = t & 255;
    const int p4   = tl & 3;
    const int cg   = tl >> 2;         // 0..63
    const int m0   = g * 8;

    const float4* X4 = (const float4*)X;
    const int base = b * 16 * 262144 + (hw0 >> 2) + p4;  // f4 units

    float4 wx[4];
#pragma unroll
    for (int k = 0; k < 4; ++k) wx[k] = make_float4(0.f, 0.f, 0.f, 0.f);

    float4 v[2][4];
#pragma unroll
    for (int k = 0; k < 4; ++k)
        v[0][k] = X4[base + m0 * 262144 + (cg + 64 * k) * 1024];

#pragma unroll
    for (int mm = 0; mm < 8; ++mm) {
        const int buf = mm & 1, nxt = buf ^ 1;
        if (mm < 7) {
#pragma unroll
            for (int k = 0; k < 4; ++k)
                v[nxt][k] = X4[base + (m0 + mm + 1) * 262144 + (cg + 64 * k) * 1024];
        }
        const float4 pm = *(const float4*)&pl[m0 + mm][4 * p4];
#pragma unroll
        for (int k = 0; k < 4; ++k) {
            wx[k].x = fmaf(pm.x, v[buf][k].x, wx[k].x);
            wx[k].y = fmaf(pm.y, v[buf][k].y, wx[k].y);
            wx[k].z = fmaf(pm.z, v[buf][k].z, wx[k].z);
            wx[k].w = fmaf(pm.w, v[buf][k].w, wx[k].w);
        }
    }

    // combine the two m-halves in LDS
    if (g == 0) {
#pragma unroll
        for (int k = 0; k < 4; ++k)
            *(float4*)&slab[(cg + 64 * k) * 20 + 4 * p4] = wx[k];
    }
    __syncthreads();
    if (g == 1) {
#pragma unroll
        for (int k = 0; k < 4; ++k) {
            float4* p = (float4*)&slab[(cg + 64 * k) * 20 + 4 * p4];
            float4 s = *p;
            s.x += wx[k].x; s.y += wx[k].y; s.z += wx[k].z; s.w += wx[k].w;
            *p = s;
        }
    }
    __syncthreads();

    // MFMA conv epilogue: out[co,px] = bv[co] + sum_o Wv[co][o] wx[o][px]
    const int w    = t >> 6;          // wave 0..7 -> co-tiles 2w, 2w+1
    const int lane = t & 63;
    const int pxl  = lane & 15;
    const int quad = lane >> 4;

    f32x4 acc[2];
#pragma unroll
    for (int i = 0; i < 2; ++i) {
        const int tt = 2 * w + i;
#pragma unroll
        for (int r = 0; r < 4; ++r)
            acc[i][r] = bv[16 * tt + quad * 4 + r];
    }

#pragma unroll
    for (int ks = 0; ks < 8; ++ks) {   // K = 256 in steps of 32
        s16x8 bfr;
#pragma unroll
        for (int j = 0; j < 8; ++j)
            bfr[j] = (short)f2bf(slab[(ks * 32 + quad * 8 + j) * 20 + pxl]);
#pragma unroll
        for (int i = 0; i < 2; ++i) {
            const int tt = 2 * w + i;
            const s16x8 afr =
                *(const s16x8*)(WvB + (16 * tt + pxl) * 256 + ks * 32 + quad * 8);
            acc[i] = __builtin_amdgcn_mfma_f32_16x16x32_bf16(afr, bfr, acc[i],
                                                             0, 0, 0);
        }
    }

    const int obase = b * 1048576 + hw0;
#pragma unroll
    for (int i = 0; i < 2; ++i) {
        const int tt = 2 * w + i;
#pragma unroll
        for (int r = 0; r < 4; ++r) {
            const int co = 16 * tt + quad * 4 + r;
            out[obase + co * 4096 + pxl] = acc[i][r];
        }
    }
}

// ---------------------------------------------------------------------------
extern "C" void kernel_launch(void* const* d_in, const int* in_sizes, int n_in,
                              void* d_out, int out_size, void* d_ws, size_t ws_size,
                              hipStream_t stream) {
    const float* TO = (const float*)d_in[0];   // [2,1024]
    const float* X  = (const float*)d_in[1];   // [2,16,256,64,64]
    const float* Wq = (const float*)d_in[2];   // [256,1024]
    const float* bq = (const float*)d_in[3];   // [256]
    const float* Wk = (const float*)d_in[4];   // [256,256]
    // d_in[5] = bk: dropped (softmax-invariant)
    const float* Wv = (const float*)d_in[6];   // [256,256]
    const float* bv = (const float*)d_in[7];   // [256]
    float* out = (float*)d_out;
    float* ws  = (float*)d_ws;

    float*          qbuf  = ws;                             // 512 f
    float*          qks   = ws + 512;                       // 512 f
    unsigned short* WvB   = (unsigned short*)(ws + 1024);   // 65536 bf16 (32768 f)
    float*          part  = ws + 33792;                     // 2,097,152 f (8 MB)
    float*          probs = ws + 33792 + 2097152;           // 131,072 f

    hipLaunchKernelGGL(prep1_kernel, dim3(32), dim3(256), 0, stream,
                       TO, Wq, bq, Wv, qbuf, WvB);
    hipLaunchKernelGGL(prep2_kernel, dim3(16), dim3(256), 0, stream,
                       qbuf, Wk, qks);
    hipLaunchKernelGGL(scores_kernel, dim3(2048), dim3(256), 0, stream,
                       X, qks, part);
    hipLaunchKernelGGL(softmax_kernel, dim3(32), dim3(256), 0, stream,
                       part, probs);
    hipLaunchKernelGGL(wxconv_kernel, dim3(512), dim3(512), 0, stream,
                       X, probs, WvB, bv, out);
}